// Round 1
// baseline (80.582 us; speedup 1.0000x reference)
//
#include <hip/hip_runtime.h>
#include <stdint.h>

typedef short bf16x8 __attribute__((ext_vector_type(8)));
typedef float f32x4 __attribute__((ext_vector_type(4)));

__device__ __forceinline__ unsigned short f2bf(float f) {
  unsigned u = __float_as_uint(f);
  u += 0x7fffu + ((u >> 16) & 1u);   // RNE round to bf16
  return (unsigned short)(u >> 16);
}

// ---------------- prep: emb fp32 -> bf16 (ws), half ||e||^2 ----------------
__global__ __launch_bounds__(256) void k_prep(const float* __restrict__ emb,
                                              unsigned short* __restrict__ embb,
                                              float* __restrict__ h2) {
  const int t = threadIdx.x;
  const int n = blockIdx.x * 8 + (t >> 5);
  const int c0 = (t & 31) * 8;
  const float* src = emb + (size_t)n * 256 + c0;
  float s = 0.f;
  union { bf16x8 v; unsigned short u[8]; } pk;
#pragma unroll
  for (int i = 0; i < 8; ++i) {
    float f = src[i];
    s += f * f;
    pk.u[i] = f2bf(f);
  }
  *(bf16x8*)(embb + (size_t)n * 256 + c0) = pk.v;
#pragma unroll
  for (int m = 1; m < 32; m <<= 1) s += __shfl_xor(s, m);
  if ((t & 31) == 0) h2[n] = 0.5f * s;
}

// ---------------- main: distances (MFMA) + argmax + gather + loss ----------
__global__ __launch_bounds__(256, 2) void k_main(
    const float* __restrict__ z, const float* __restrict__ emb,
    const unsigned short* __restrict__ embb, const float* __restrict__ h2,
    float* __restrict__ out, float* __restrict__ acc_g) {

  __shared__ __align__(16) unsigned short lA[64 * 256];     // 32 KB, [row][k] swizzled
  __shared__ __align__(16) unsigned short lB[2][128 * 64];  // 2x16 KB, [n][k] swizzled
  __shared__ float candv[2][64];
  __shared__ int   candi[2][64];
  __shared__ float bestv[64];
  __shared__ int   besti[64];
  __shared__ float red[4];

  const int t = threadIdx.x;
  const int lane = t & 63;
  const int w = t >> 6;            // wave 0..3
  const int wm = w >> 1, wn = w & 1;
  const int blk = blockIdx.x;
  const int b = blk >> 4;
  const int hw0 = (blk & 15) * 64;

  // stage (bn,ks) B tile [128 n][64 k] into lB[buf]; LDS linear dest,
  // swizzle baked into per-lane GLOBAL source address (m173 pattern).
  auto stageB = [&](int st, int buf) {
    const int bn = st >> 2, ks = st & 3;
    const unsigned short* base = embb + (size_t)(bn * 128) * 256 + ks * 64;
#pragma unroll
    for (int rd = 0; rd < 4; ++rd) {
      const int nl = rd * 32 + (t >> 3);     // local emb row 0..127
      const int p  = t & 7;                  // physical 16B slot
      const int kc = (p ^ (nl & 7)) * 8;     // logical k-chunk
      const unsigned short* g = base + (size_t)nl * 256 + kc;
      char* l = (char*)(&lB[buf][0]) + rd * 4096 + w * 1024; // wave-uniform base
      __builtin_amdgcn_global_load_lds((const __attribute__((address_space(1))) void*)g,
                                       (__attribute__((address_space(3))) void*)l,
                                       16, 0, 0);
    }
  };

  stageB(0, 0);   // overlap first B stage with phase A

  // ---- phase A: z rows -> lA bf16 (transposed, swizzled), sumsq in fp32
  {
    const int r = lane;                                   // row = hw
    const float* zp = z + (size_t)b * 262144 + hw0 + r;   // + c*1024
    const int c0 = w * 64;
    float ss = 0.f;
#pragma unroll
    for (int i = 0; i < 8; ++i) {
      union { bf16x8 v; unsigned short u[8]; } pk;
#pragma unroll
      for (int j = 0; j < 8; ++j) {
        float f = zp[(size_t)(c0 + i * 8 + j) * 1024];
        ss += f * f;
        pk.u[j] = f2bf(f);
      }
      const int p = w * 8 + (i ^ (r & 7));                // swizzled 16B slot
      *(bf16x8*)((char*)lA + r * 512 + p * 16) = pk.v;
    }
#pragma unroll
    for (int m = 1; m < 64; m <<= 1) ss += __shfl_xor(ss, m);
    if (lane == 0) red[w] = ss;
    if (t < 64) { bestv[t] = -1e30f; besti[t] = 0; }
  }
  __syncthreads();   // drains stageB(0) vmcnt + lA lgkm

  f32x4 acc[2][4];
  const int l15 = lane & 15;
  const int l4  = lane >> 4;

  for (int st = 0; st < 32; ++st) {
    const int cur = st & 1;
    const int ks  = st & 3;
    const int bn  = st >> 2;
    if (ks == 0) {
#pragma unroll
      for (int mi = 0; mi < 2; ++mi)
#pragma unroll
        for (int ni = 0; ni < 4; ++ni)
#pragma unroll
          for (int q = 0; q < 4; ++q) acc[mi][ni][q] = 0.f;
    }
    if (st < 31) stageB(st + 1, cur ^ 1);

    bf16x8 af[2][2], bfr[4][2];
#pragma unroll
    for (int mi = 0; mi < 2; ++mi) {
      const int r = wm * 32 + mi * 16 + l15;
#pragma unroll
      for (int kk = 0; kk < 2; ++kk) {
        const int p = ks * 8 + ((kk * 4 + l4) ^ (r & 7));
        af[mi][kk] = *(const bf16x8*)((const char*)lA + r * 512 + p * 16);
      }
    }
#pragma unroll
    for (int ni = 0; ni < 4; ++ni) {
      const int n = wn * 64 + ni * 16 + l15;
#pragma unroll
      for (int kk = 0; kk < 2; ++kk) {
        const int p = (kk * 4 + l4) ^ (n & 7);
        bfr[ni][kk] = *(const bf16x8*)((const char*)&lB[cur][0] + n * 128 + p * 16);
      }
    }
#pragma unroll
    for (int kk = 0; kk < 2; ++kk)
#pragma unroll
      for (int mi = 0; mi < 2; ++mi)
#pragma unroll
        for (int ni = 0; ni < 4; ++ni)
          acc[mi][ni] = __builtin_amdgcn_mfma_f32_16x16x32_bf16(
              af[mi][kk], bfr[ni][kk], acc[mi][ni], 0, 0, 0);

    if (ks == 3) {   // fold argmax for this 128-embedding chunk
      const int colbase = bn * 128 + wn * 64 + l15;
      float h[4];
#pragma unroll
      for (int ni = 0; ni < 4; ++ni) h[ni] = h2[colbase + ni * 16];
#pragma unroll
      for (int mi = 0; mi < 2; ++mi) {
#pragma unroll
        for (int j = 0; j < 4; ++j) {
          float bv = acc[mi][0][j] - h[0];
          int   bi = colbase;
#pragma unroll
          for (int ni = 1; ni < 4; ++ni) {
            float v = acc[mi][ni][j] - h[ni];
            int  ci = colbase + ni * 16;
            if (v > bv || (v == bv && ci < bi)) { bv = v; bi = ci; }
          }
#pragma unroll
          for (int m = 1; m < 16; m <<= 1) {
            float ov = __shfl_xor(bv, m);
            int   oi = __shfl_xor(bi, m);
            if (ov > bv || (ov == bv && oi < bi)) { bv = ov; bi = oi; }
          }
          if (l15 == 0) {
            const int row = wm * 32 + mi * 16 + l4 * 4 + j;
            candv[wn][row] = bv;
            candi[wn][row] = bi;
          }
        }
      }
    }
    __syncthreads();
    if (ks == 3 && t < 64) {   // merge the two wave-columns + running best
      float v0 = candv[0][t]; int i0 = candi[0][t];
      float v1 = candv[1][t]; int i1 = candi[1][t];
      if (v1 > v0 || (v1 == v0 && i1 < i0)) { v0 = v1; i0 = i1; }
      if (v0 > bestv[t] || (v0 == bestv[t] && i0 < besti[t])) { bestv[t] = v0; besti[t] = i0; }
    }
  }
  __syncthreads();

  // ---- loss partial: sum(z^2) - 2*sum(t*)
  if (w == 0) {
    float tv = bestv[lane];
#pragma unroll
    for (int m = 1; m < 64; m <<= 1) tv += __shfl_xor(tv, m);
    if (lane == 0) atomicAdd(acc_g, red[0] + red[1] + red[2] + red[3] - 2.f * tv);
  }

  // ---- gather emb fp32 rows, write quantized in [B,C,H,W] (coalesced over hw)
  const int hh = lane;
  const int idx = besti[hh];
  const float* ep = emb + (size_t)idx * 256;
  float* op = out + (size_t)b * 262144 + hw0 + hh;
#pragma unroll
  for (int rd = 0; rd < 16; ++rd) {
    const int cb = w * 4 + rd * 16;
    const float4 v = *(const float4*)(ep + cb);
    op[(size_t)(cb + 0) * 1024] = v.x;
    op[(size_t)(cb + 1) * 1024] = v.y;
    op[(size_t)(cb + 2) * 1024] = v.z;
    op[(size_t)(cb + 3) * 1024] = v.w;
  }
}

// ---------------- finalize loss ----------------
__global__ void k_fin(const float* __restrict__ acc_g, float* __restrict__ lossp) {
  if (threadIdx.x == 0) lossp[0] = 1.25f * acc_g[0] * (1.0f / 8388608.0f);
}

extern "C" void kernel_launch(void* const* d_in, const int* in_sizes, int n_in,
                              void* d_out, int out_size, void* d_ws, size_t ws_size,
                              hipStream_t stream) {
  (void)in_sizes; (void)n_in; (void)ws_size;
  const float* z   = (const float*)d_in[0];
  const float* emb = (const float*)d_in[1];
  float* out = (float*)d_out;
  char*  ws  = (char*)d_ws;
  unsigned short* embb = (unsigned short*)ws;          // 524288 B
  float* h2  = (float*)(ws + 524288);                  // 4096 B
  float* acc = (float*)(ws + 524288 + 4096);           // 4 B

  hipMemsetAsync(acc, 0, 4, stream);
  hipLaunchKernelGGL(k_prep, dim3(128), dim3(256), 0, stream, emb, embb, h2);
  hipLaunchKernelGGL(k_main, dim3(512), dim3(256), 0, stream, z, emb, embb, h2, out, acc);
  hipLaunchKernelGGL(k_fin, dim3(1), dim3(64), 0, stream, acc, out + (size_t)out_size - 1);
}